// Round 2
// baseline (105.896 us; speedup 1.0000x reference)
//
#include <hip/hip_runtime.h>
#include <hip/hip_bf16.h>

#define B_TOTAL 262144
#define K_CB    512
#define D_DIM   3
#define BLOCK   256

__global__ __launch_bounds__(BLOCK) void vq_kernel(
    const float* __restrict__ ze, const float* __restrict__ e,
    float* __restrict__ z_out, float* __restrict__ zq_out)
{
    __shared__ __align__(16) float se[K_CB * D_DIM];
    for (int i = threadIdx.x; i < K_CB * D_DIM; i += BLOCK) se[i] = e[i];
    __syncthreads();

    const int b = blockIdx.x * BLOCK + threadIdx.x;
    const float x0 = ze[b * 3 + 0];
    const float x1 = ze[b * 3 + 1];
    const float x2 = ze[b * 3 + 2];

    float bd0 = 3.4e38f, bd1 = 3.4e38f, bd2 = 3.4e38f;
    int   bi0 = 0,       bi1 = 0,       bi2 = 0;

    const float4* se4 = (const float4*)se;

    // exact fp32 arithmetic, ascending k, strict '<'  => matches np.argmin ties
#pragma unroll 4
    for (int k4 = 0; k4 < K_CB / 4; ++k4) {
        const float4 va = se4[k4 * 3 + 0]; // e[k][0..2], e[k+1][0]
        const float4 vb = se4[k4 * 3 + 1]; // e[k+1][1..2], e[k+2][0..1]
        const float4 vc = se4[k4 * 3 + 2]; // e[k+2][2], e[k+3][0..2]
        const int k = k4 * 4;

        {   // k + 0
            float t0 = x0 - va.x, t1 = x1 - va.y, t2 = x2 - va.z;
            float d0 = t0*t0, d1 = t1*t1, d2 = t2*t2;
            bool c0 = d0 < bd0; bd0 = c0 ? d0 : bd0; bi0 = c0 ? k : bi0;
            bool c1 = d1 < bd1; bd1 = c1 ? d1 : bd1; bi1 = c1 ? k : bi1;
            bool c2 = d2 < bd2; bd2 = c2 ? d2 : bd2; bi2 = c2 ? k : bi2;
        }
        {   // k + 1
            float t0 = x0 - va.w, t1 = x1 - vb.x, t2 = x2 - vb.y;
            float d0 = t0*t0, d1 = t1*t1, d2 = t2*t2;
            bool c0 = d0 < bd0; bd0 = c0 ? d0 : bd0; bi0 = c0 ? (k+1) : bi0;
            bool c1 = d1 < bd1; bd1 = c1 ? d1 : bd1; bi1 = c1 ? (k+1) : bi1;
            bool c2 = d2 < bd2; bd2 = c2 ? d2 : bd2; bi2 = c2 ? (k+1) : bi2;
        }
        {   // k + 2
            float t0 = x0 - vb.z, t1 = x1 - vb.w, t2 = x2 - vc.x;
            float d0 = t0*t0, d1 = t1*t1, d2 = t2*t2;
            bool c0 = d0 < bd0; bd0 = c0 ? d0 : bd0; bi0 = c0 ? (k+2) : bi0;
            bool c1 = d1 < bd1; bd1 = c1 ? d1 : bd1; bi1 = c1 ? (k+2) : bi1;
            bool c2 = d2 < bd2; bd2 = c2 ? d2 : bd2; bi2 = c2 ? (k+2) : bi2;
        }
        {   // k + 3
            float t0 = x0 - vc.y, t1 = x1 - vc.z, t2 = x2 - vc.w;
            float d0 = t0*t0, d1 = t1*t1, d2 = t2*t2;
            bool c0 = d0 < bd0; bd0 = c0 ? d0 : bd0; bi0 = c0 ? (k+3) : bi0;
            bool c1 = d1 < bd1; bd1 = c1 ? d1 : bd1; bi1 = c1 ? (k+3) : bi1;
            bool c2 = d2 < bd2; bd2 = c2 ? d2 : bd2; bi2 = c2 ? (k+3) : bi2;
        }
    }

    // gather zq[b,d] = e[z[b,d], d] from LDS
    const float q0 = se[bi0 * 3 + 0];
    const float q1 = se[bi1 * 3 + 1];
    const float q2 = se[bi2 * 3 + 2];

    // float32 outputs: z as index-valued floats, zq exact fp32
    z_out [b * 3 + 0] = (float)bi0;
    z_out [b * 3 + 1] = (float)bi1;
    z_out [b * 3 + 2] = (float)bi2;
    zq_out[b * 3 + 0] = q0;
    zq_out[b * 3 + 1] = q1;
    zq_out[b * 3 + 2] = q2;
}

extern "C" void kernel_launch(void* const* d_in, const int* in_sizes, int n_in,
                              void* d_out, int out_size, void* d_ws, size_t ws_size,
                              hipStream_t stream) {
    const float* ze = (const float*)d_in[0];
    const float* e  = (const float*)d_in[1];
    float* z_out  = (float*)d_out;                       // z  : B*D float32
    float* zq_out = z_out + (size_t)B_TOTAL * D_DIM;     // zq : B*D float32

    vq_kernel<<<B_TOTAL / BLOCK, BLOCK, 0, stream>>>(ze, e, z_out, zq_out);
}

// Round 3
// 100.454 us; speedup vs baseline: 1.0542x; 1.0542x over previous
//
#include <hip/hip_runtime.h>

#define B_TOTAL 262144
#define K_CB    512
#define D_DIM   3
#define BLOCK   256

// monotone map fp32 bits -> uint32 (ascending float => ascending uint)
__device__ __forceinline__ unsigned int mono32(unsigned int u) {
    unsigned int m = (u & 0x80000000u) ? 0xFFFFFFFFu : 0x80000000u;
    return u ^ m;
}

__global__ __launch_bounds__(BLOCK) void vq_sorted_kernel(
    const float* __restrict__ ze, const float* __restrict__ e,
    float* __restrict__ z_out, float* __restrict__ zq_out)
{
    // keys: (mono(value) << 32) | orig_idx  => lexicographic (value, idx) sort
    __shared__ unsigned long long keys[D_DIM][K_CB]; // 12 KB
    __shared__ float sval[D_DIM][K_CB];              // 6 KB
    __shared__ int   sidx[D_DIM][K_CB];              // 6 KB

    const int tid = threadIdx.x;

    // ---- load + pack: e is [K][D] row-major ----
    for (int i = tid; i < K_CB * D_DIM; i += BLOCK) {
        int k = i / D_DIM;
        int d = i - k * D_DIM;
        unsigned int vb = __float_as_uint(e[i]);
        keys[d][k] = ((unsigned long long)mono32(vb) << 32) | (unsigned int)k;
    }
    __syncthreads();

    // ---- bitonic sort, ascending, all 3 dims concurrently ----
    for (unsigned int k = 2; k <= K_CB; k <<= 1) {
        for (unsigned int j = k >> 1; j > 0; j >>= 1) {
            for (unsigned int t = tid; t < K_CB; t += BLOCK) {
                unsigned int ixj = t ^ j;
                if (ixj > t) {
                    const bool asc = ((t & k) == 0);
                    #pragma unroll
                    for (int d = 0; d < D_DIM; ++d) {
                        unsigned long long a = keys[d][t];
                        unsigned long long b = keys[d][ixj];
                        if ((a > b) == asc) { keys[d][t] = b; keys[d][ixj] = a; }
                    }
                }
            }
            __syncthreads();
        }
    }

    // ---- unpack to (value, idx) arrays ----
    for (int i = tid; i < K_CB * D_DIM; i += BLOCK) {
        int d = i / K_CB;
        int p = i - d * K_CB;
        unsigned long long key = keys[d][p];
        unsigned int hv = (unsigned int)(key >> 32);
        unsigned int vb = (hv & 0x80000000u) ? (hv ^ 0x80000000u) : ~hv;
        sval[d][p] = __uint_as_float(vb);
        sidx[d][p] = (int)(key & 0xFFFFFFFFu);
    }
    __syncthreads();

    // ---- query: 1 b per thread, 3 dims ----
    const int b = blockIdx.x * BLOCK + tid;
    const float x0 = ze[b * 3 + 0];
    const float x1 = ze[b * 3 + 1];
    const float x2 = ze[b * 3 + 2];
    const float xs[D_DIM] = { x0, x1, x2 };

    #pragma unroll
    for (int d = 0; d < D_DIM; ++d) {
        const float xv = xs[d];

        // binary search: invariant sval[lo] <= xv < sval[hi] (virtual sentinels)
        int lo = -1, hi = K_CB;
        #pragma unroll
        for (int it = 0; it < 9; ++it) {
            int mid = (lo + hi) >> 1;           // always in [0, 511]
            bool le = sval[d][mid] <= xv;
            lo = le ? mid : lo;
            hi = le ? hi : mid;
        }

        // left candidate: nearest value <= xv; walk to first entry of equal-value
        // run (sorted by (value,idx) => that's the min original index)
        float dl = 3.402823466e38f, vl = 0.0f; int il = 0;
        if (lo >= 0) {
            vl = sval[d][lo];
            int p = lo;
            while (p > 0 && sval[d][p - 1] == vl) --p;   // exact-duplicate handling
            il = sidx[d][p];
            float t = xv - vl;   // identical fp32 arithmetic to reference
            dl = t * t;
        }
        // right candidate: nearest value > xv (group head == lo+1 by construction)
        float dr = 3.402823466e38f, vr = 0.0f; int ir = 0;
        if (lo < K_CB - 1) {
            vr = sval[d][lo + 1];
            ir = sidx[d][lo + 1];
            float t = xv - vr;
            dr = t * t;
        }

        // np.argmin semantics: strict min; tie -> smaller original index
        const bool pickR = (dr < dl) || ((dr == dl) && (ir < il));
        z_out [b * 3 + d] = (float)(pickR ? ir : il);
        zq_out[b * 3 + d] = pickR ? vr : vl;
    }
}

extern "C" void kernel_launch(void* const* d_in, const int* in_sizes, int n_in,
                              void* d_out, int out_size, void* d_ws, size_t ws_size,
                              hipStream_t stream) {
    const float* ze = (const float*)d_in[0];
    const float* e  = (const float*)d_in[1];
    float* z_out  = (float*)d_out;                    // z  : B*D float32
    float* zq_out = z_out + (size_t)B_TOTAL * D_DIM;  // zq : B*D float32

    vq_sorted_kernel<<<B_TOTAL / BLOCK, BLOCK, 0, stream>>>(ze, e, z_out, zq_out);
}

// Round 4
// 71.202 us; speedup vs baseline: 1.4873x; 1.4108x over previous
//
#include <hip/hip_runtime.h>

#define B_TOTAL 262144
#define K_CB    512
#define D_DIM   3
#define BLOCK   256

// monotone map fp32 bits -> uint32 (ascending float => ascending uint)
__device__ __forceinline__ unsigned int mono32(unsigned int u) {
    unsigned int m = (u & 0x80000000u) ? 0xFFFFFFFFu : 0x80000000u;
    return u ^ m;
}

// ---------------- kernel 1: rank-sort the tiny codebook into d_ws -------------
// grid = D_DIM * 2 blocks; block (d, half) ranks entries [half*256, half*256+256)
// of dim d. ws layout: sval[3][512] floats, then sidx[3][512] ints.
__global__ __launch_bounds__(BLOCK) void rank_kernel(
    const float* __restrict__ e, float* __restrict__ ws_val, int* __restrict__ ws_idx)
{
    const int d    = blockIdx.x >> 1;
    const int half = blockIdx.x & 1;
    const int tid  = threadIdx.x;

    __shared__ unsigned long long key[K_CB];
    __shared__ float              val[K_CB];

    for (int k = tid; k < K_CB; k += BLOCK) {
        float v = e[k * D_DIM + d];
        key[k] = ((unsigned long long)mono32(__float_as_uint(v)) << 32) | (unsigned int)k;
        val[k] = v;
    }
    __syncthreads();

    const int i = half * BLOCK + tid;           // my entry
    const unsigned long long mykey = key[i];
    int rank = 0;
    #pragma unroll 8
    for (int j = 0; j < K_CB; ++j)              // wave-uniform LDS reads: broadcast
        rank += (key[j] < mykey) ? 1 : 0;

    ws_val[d * K_CB + rank] = val[i];
    ws_idx[d * K_CB + rank] = i;
}

// ---------------- kernel 2: binary search over sorted codebook ----------------
__global__ __launch_bounds__(BLOCK) void vq_search_kernel(
    const float* __restrict__ ze,
    const float* __restrict__ ws_val, const int* __restrict__ ws_idx,
    float* __restrict__ z_out, float* __restrict__ zq_out)
{
    __shared__ float sval[D_DIM][K_CB];   // 6 KB
    __shared__ int   sidx[D_DIM][K_CB];   // 6 KB

    const int tid = threadIdx.x;
    for (int i = tid; i < D_DIM * K_CB; i += BLOCK) {
        ((float*)sval)[i] = ws_val[i];
        ((int*)sidx)[i]   = ws_idx[i];
    }
    __syncthreads();

    const int b = blockIdx.x * BLOCK + tid;
    const float xs[D_DIM] = { ze[b * 3 + 0], ze[b * 3 + 1], ze[b * 3 + 2] };

    #pragma unroll
    for (int d = 0; d < D_DIM; ++d) {
        const float xv = xs[d];

        // binary search: invariant sval[lo] <= xv < sval[hi] (virtual sentinels)
        int lo = -1, hi = K_CB;
        #pragma unroll
        for (int it = 0; it < 9; ++it) {
            int mid = (lo + hi) >> 1;           // always in [0, 511]
            bool le = sval[d][mid] <= xv;
            lo = le ? mid : lo;
            hi = le ? hi : mid;
        }

        // left candidate: nearest value <= xv; walk back to first entry of the
        // equal-value run (sorted by (value,idx) => that's the min orig index)
        float dl = 3.402823466e38f, vl = 0.0f; int il = 0;
        if (lo >= 0) {
            vl = sval[d][lo];
            int p = lo;
            while (p > 0 && sval[d][p - 1] == vl) --p;   // exact-duplicate handling
            il = sidx[d][p];
            float t = xv - vl;                  // identical fp32 arithmetic to ref
            dl = t * t;
        }
        // right candidate: nearest value > xv (group head == lo+1 by construction)
        float dr = 3.402823466e38f, vr = 0.0f; int ir = 0;
        if (lo < K_CB - 1) {
            vr = sval[d][lo + 1];
            ir = sidx[d][lo + 1];
            float t = xv - vr;
            dr = t * t;
        }

        // np.argmin semantics: strict min; tie -> smaller original index
        const bool pickR = (dr < dl) || ((dr == dl) && (ir < il));
        z_out [b * 3 + d] = (float)(pickR ? ir : il);
        zq_out[b * 3 + d] = pickR ? vr : vl;
    }
}

extern "C" void kernel_launch(void* const* d_in, const int* in_sizes, int n_in,
                              void* d_out, int out_size, void* d_ws, size_t ws_size,
                              hipStream_t stream) {
    const float* ze = (const float*)d_in[0];
    const float* e  = (const float*)d_in[1];
    float* z_out  = (float*)d_out;                    // z  : B*D float32
    float* zq_out = z_out + (size_t)B_TOTAL * D_DIM;  // zq : B*D float32

    float* ws_val = (float*)d_ws;                     // [3][512] sorted values
    int*   ws_idx = (int*)(ws_val + D_DIM * K_CB);    // [3][512] original indices

    rank_kernel     <<<D_DIM * 2,       BLOCK, 0, stream>>>(e, ws_val, ws_idx);
    vq_search_kernel<<<B_TOTAL / BLOCK, BLOCK, 0, stream>>>(ze, ws_val, ws_idx,
                                                            z_out, zq_out);
}